// Round 7
// baseline (10876.105 us; speedup 1.0000x reference)
//
#include <hip/hip_runtime.h>
#include <hip/hip_bf16.h>
#include <stdint.h>

#define KKTOT 100000
#define BAP   2048
#define KPADMAX 100352   // 49*2048

typedef _Float16 f16x8 __attribute__((ext_vector_type(8)));
typedef float    f32x4 __attribute__((ext_vector_type(4)));

// ---- constants (match reference f32 arithmetic) ----
__device__ __constant__ float KCf  = (float)(4.0 * 3.14159265358979323846 * 77.0e9 / 299792458.0);
__device__ __constant__ float I2PA = (float)(0.15915494309189534940823);
__device__ __constant__ float I2PB = (float)(0.15915494309189534940823 - (double)(float)(0.15915494309189534940823));

__device__ __forceinline__ float phase_frac(float dy, float dxx) {
    float d2 = fmaf(dy, dy, fmaf(dxx, dxx, 0.09f));
    float ph = KCf * sqrtf(d2);                  // f32 phase, same rounding class as reference
    float h  = ph * I2PA;
    float l  = fmaf(ph, I2PA, -h);               // exact residual of the product
    l = fmaf(ph, I2PB, l);                       // correction for f32(1/2pi) error
    return (h - floorf(h)) + l;                  // revolutions
}

__device__ __forceinline__ void gload16(const void* g, void* l) {
    __builtin_amdgcn_global_load_lds(
        (__attribute__((address_space(1))) void*)(uintptr_t)g,
        (__attribute__((address_space(3))) void*)(uint32_t)(uintptr_t)l,
        16, 0, 0);
}

__device__ __forceinline__ float2 cmulf(float2 a, float2 b) {
    return make_float2(a.x*b.x - a.y*b.y, a.x*b.y + a.y*b.x);
}

// ---------------- decode py (int32) ----------------
__global__ __launch_bounds__(256) void decode_k(const float* __restrict__ sar, const int* __restrict__ py,
                                                float* __restrict__ ay, float* __restrict__ ax, float* __restrict__ rd) {
    int i = blockIdx.x * 256 + threadIdx.x;
    if (i >= KKTOT) return;
    int p = py[i];
    int iy = p & 511, ix = p >> 9;
    ay[i] = ((float)iy + 0.5f - 256.0f) * 1e-3f;
    ax[i] = ((float)ix + 0.5f - 256.0f) * 1e-3f;
    rd[i] = sar[p];
}

// ---------------- generate C=cos, S=sin as f16, layout [2048][Kc] ----------------
__global__ __launch_bounds__(256) void gen_cs(_Float16* __restrict__ C, _Float16* __restrict__ S,
                                              const float* __restrict__ ay, const float* __restrict__ ax,
                                              int k0, int Kc) {
    int j = blockIdx.y;
    long long kk = ((long long)blockIdx.x * 256 + threadIdx.x) * 8;
    size_t o = (size_t)j * Kc + kk;
    long long kg = (long long)k0 + kk;
    f16x8 cv, sv;
    if (j < 2000 && kg < KKTOT) {
        int jy = j % 40, jx = j / 40;
        float why = ((float)jy * (200.0f/39.0f) - 100.0f) * 1e-3f;   // wh2[jy]
        float whx = ((float)jx * (200.0f/49.0f) - 100.0f) * 1e-3f;   // wh1[jx]
        float4 a0 = *(const float4*)(ay + kg);
        float4 a1 = *(const float4*)(ay + kg + 4);
        float4 b0 = *(const float4*)(ax + kg);
        float4 b1 = *(const float4*)(ax + kg + 4);
        float ayv[8] = {a0.x,a0.y,a0.z,a0.w,a1.x,a1.y,a1.z,a1.w};
        float axv[8] = {b0.x,b0.y,b0.z,b0.w,b1.x,b1.y,b1.z,b1.w};
        #pragma unroll
        for (int e = 0; e < 8; ++e) {
            float fr = phase_frac(ayv[e]-why, axv[e]-whx);
            cv[e] = (_Float16)__builtin_amdgcn_cosf(fr);
            sv[e] = (_Float16)__builtin_amdgcn_sinf(fr);
        }
    } else {
        #pragma unroll
        for (int e = 0; e < 8; ++e) { cv[e] = (_Float16)0.f; sv[e] = (_Float16)0.f; }
    }
    *(f16x8*)(C + o) = cv;
    *(f16x8*)(S + o) = sv;
}

// ---------------- MFMA Gram GEMM: out[m][n] += sum_k A[k,m]*B[k,n] ----------------
__global__ __launch_bounds__(256) void gemm_gram(const _Float16* __restrict__ A0, const _Float16* __restrict__ B0,
                                                 const _Float16* __restrict__ A1, const _Float16* __restrict__ B1,
                                                 float* __restrict__ out0, float* __restrict__ out1,
                                                 int kiters, int kstride, int npass) {
    __shared__ _Float16 ldsA[8192];
    __shared__ _Float16 ldsB[8192];
    const int t = threadIdx.x;
    const int w = t >> 6;
    const int lane = t & 63;
    const int mi = blockIdx.x, ni = blockIdx.y, z = blockIdx.z;
    float* out = z ? out1 : out0;

    f32x4 acc[4][4];
    #pragma unroll
    for (int a = 0; a < 4; ++a)
        #pragma unroll
        for (int b = 0; b < 4; ++b) acc[a][b] = (f32x4){0.f,0.f,0.f,0.f};

    size_t aoff[4], boff[4];
    #pragma unroll
    for (int r = 0; r < 4; ++r) {
        int c = r * 256 + t;
        int jl = c >> 3;
        int ks = (c & 7) ^ (jl & 7);
        aoff[r] = (size_t)(mi*128 + jl) * kstride + ks*8;
        boff[r] = (size_t)(ni*128 + jl) * kstride + ks*8;
    }
    const int wm = w & 1, wn = w >> 1;
    const int q = lane >> 4, lm = lane & 15;
    const int ajl = wm*64 + lm;
    const int aoffl = (ajl*8 + (q ^ (ajl & 7))) * 16;
    const int bjl = wn*64 + lm;
    const int boffl = (bjl*8 + (q ^ (bjl & 7))) * 16;

    const _Float16* Aps[2] = {A0, A1};
    const _Float16* Bps[2] = {B0, B1};
    const int kh = kiters >> 1;
    for (int pass = 0; pass < npass; ++pass) {
        const _Float16* Ap = Aps[pass];
        const _Float16* Bp = Bps[pass];
        for (int kt = z*kh; kt < (z+1)*kh; ++kt) {
            __syncthreads();
            const _Float16* ga = Ap + (size_t)kt * 64;
            const _Float16* gb = Bp + (size_t)kt * 64;
            #pragma unroll
            for (int r = 0; r < 4; ++r) {
                gload16(ga + aoff[r], (char*)ldsA + (size_t)(r*256 + w*64)*16);
                gload16(gb + boff[r], (char*)ldsB + (size_t)(r*256 + w*64)*16);
            }
            __syncthreads();
            #pragma unroll
            for (int ks = 0; ks < 2; ++ks) {
                f16x8 af[4], bf[4];
                #pragma unroll
                for (int mt = 0; mt < 4; ++mt)
                    af[mt] = *(const f16x8*)((const char*)ldsA + ((aoffl ^ (ks*64)) + mt*2048));
                #pragma unroll
                for (int nt = 0; nt < 4; ++nt)
                    bf[nt] = *(const f16x8*)((const char*)ldsB + ((boffl ^ (ks*64)) + nt*2048));
                #pragma unroll
                for (int mt = 0; mt < 4; ++mt)
                    #pragma unroll
                    for (int nt = 0; nt < 4; ++nt)
                        acc[mt][nt] = __builtin_amdgcn_mfma_f32_16x16x32_f16(af[mt], bf[nt], acc[mt][nt], 0, 0, 0);
            }
        }
    }
    #pragma unroll
    for (int mt = 0; mt < 4; ++mt) {
        #pragma unroll
        for (int nt = 0; nt < 4; ++nt) {
            int row0 = mi*128 + wm*64 + mt*16 + q*4;
            int col  = ni*128 + wn*64 + nt*16 + lm;
            float* op = out + (size_t)row0 * BAP + col;
            #pragma unroll
            for (int rr = 0; rr < 4; ++rr)
                op[(size_t)rr * BAP] += acc[mt][nt][rr];
        }
    }
}

// ---------------- xd = DI * Hp^H rd ----------------
__global__ __launch_bounds__(256) void xd_init(const float* __restrict__ ay, const float* __restrict__ ax,
                                               const float* __restrict__ rd, float2* __restrict__ xd) {
    int j = blockIdx.x;
    int t = threadIdx.x;
    __shared__ float redr[256], redi[256];
    if (j >= 2000) { if (t == 0) xd[j] = make_float2(0.f, 0.f); return; }
    int jy = j % 40, jx = j / 40;
    float why = ((float)jy * (200.0f/39.0f) - 100.0f) * 1e-3f;
    float whx = ((float)jx * (200.0f/49.0f) - 100.0f) * 1e-3f;
    float sr = 0.f, si = 0.f;
    for (int i = t; i < KKTOT; i += 256) {
        float fr = phase_frac(ay[i]-why, ax[i]-whx);
        float r = rd[i];
        sr = fmaf(r, __builtin_amdgcn_cosf(fr), sr);
        si = fmaf(r, __builtin_amdgcn_sinf(fr), si);
    }
    redr[t] = sr; redi[t] = si;
    __syncthreads();
    for (int s2 = 128; s2 > 0; s2 >>= 1) {
        if (t < s2) { redr[t] += redr[t+s2]; redi[t] += redi[t+s2]; }
        __syncthreads();
    }
    if (t == 0) xd[j] = make_float2(0.01f * redr[0], -0.01f * redi[0]);
}

// ---------------- G = DI*(R, P - P^T) ----------------
__global__ __launch_bounds__(256) void build_G(const float* __restrict__ R0, const float* __restrict__ R1,
                                               const float* __restrict__ P0, const float* __restrict__ P1,
                                               float2* __restrict__ G) {
    int m = blockIdx.y;
    int n = blockIdx.x * 256 + threadIdx.x;
    size_t mn = (size_t)m * BAP + n, nm = (size_t)n * BAP + m;
    float re = 0.01f * (R0[mn] + R1[mn]);
    float im = 0.01f * ((P0[mn] + P1[mn]) - (P0[nm] + P1[nm]));
    G[mn] = make_float2(re, im);
}

// ---------------- panel factorization (64x64 sequential core) ----------------
// Validated bit-exact against the brute-force reference scan (r1/r2 vs r6).
__global__ __launch_bounds__(256) void panel_factor(const float2* __restrict__ G, const float2* __restrict__ xd,
                                                    float2* __restrict__ Tp, float2* __restrict__ Wp,
                                                    float2* __restrict__ dinv, float2* __restrict__ v, int p0) {
    __shared__ float2 Rcm[64*65];   // Rcm[c*65+i] = R[i][c]
    __shared__ float2 rowj[64];
    __shared__ float2 xdp[64];
    int t = threadIdx.x;
    int i = t & 63, cg = t >> 6;
    int cbase = cg * 16;
    #pragma unroll
    for (int r = 0; r < 16; ++r) {
        int e = t + 256*r;
        int ci = e & 63, ri = e >> 6;
        Rcm[ci*65 + ri] = G[(size_t)(p0+ri)*BAP + p0 + ci];
    }
    if (cg == 0) xdp[i] = xd[p0 + i];
    __syncthreads();
    for (int j = 0; j < 64; ++j) {
        float2 pr = Rcm[j*65 + j];
        float dr = 1.0f + pr.x, dii = pr.y;
        float idn = 1.0f / (dr*dr + dii*dii);
        float2 dv = make_float2(dr*idn, -dii*idn);
        float2 col = Rcm[j*65 + i];
        float2 tp = cmulf(col, dv);
        float2 vj = xdp[j];
        if (i == j) {
            for (int c = cbase; c < cbase+16; ++c) {
                float2 rv = Rcm[c*65 + j];
                rowj[c] = rv;
                Wp[j*64 + c] = rv;
            }
            if (cg == 0) { dinv[j] = dv; v[j] = vj; }
        }
        __syncthreads();
        for (int c = cbase; c < cbase+16; ++c) {
            float2 rj = rowj[c];
            float2 cur = Rcm[c*65 + i];
            cur.x -= tp.x*rj.x - tp.y*rj.y;
            cur.y -= tp.x*rj.y + tp.y*rj.x;
            Rcm[c*65 + i] = cur;
        }
        if (cg == 0) {
            Tp[i*64 + j] = tp;
            float2 xi = xdp[i];
            xi.x -= tp.x*vj.x - tp.y*vj.y;
            xi.y -= tp.x*vj.y + tp.y*vj.x;
            xdp[i] = xi;
        }
        __syncthreads();
    }
}

// ---------------- T (2048x64) / W (64x2048) recurrences; role 0 also updates xd ----------------
__global__ __launch_bounds__(64) void panel_TW(const float2* __restrict__ G, float2* __restrict__ xd,
                                               float2* __restrict__ T, float2* __restrict__ W,
                                               const float2* __restrict__ Tp, const float2* __restrict__ Wp,
                                               const float2* __restrict__ dinv, const float2* __restrict__ v, int p0) {
    __shared__ float2 src[64][64];
    __shared__ float2 loc[64][64];
    int t = threadIdx.x;
    if (blockIdx.y == 0) {
        int r = blockIdx.x * 64 + t;
        const float4* gp = (const float4*)(G + (size_t)r * BAP + p0);
        #pragma unroll
        for (int jj = 0; jj < 32; ++jj) {
            float4 qd = gp[jj];
            src[2*jj][t]   = make_float2(qd.x, qd.y);
            src[2*jj+1][t] = make_float2(qd.z, qd.w);
        }
        float2 xacc = xd[r];
        for (int j = 0; j < 64; ++j) {
            float2 a = src[j][t];
            for (int k = 0; k < j; ++k) {
                float2 wkj = Wp[k*64 + j];
                float2 lk = loc[k][t];
                a.x -= lk.x*wkj.x - lk.y*wkj.y;
                a.y -= lk.x*wkj.y + lk.y*wkj.x;
            }
            float2 tj = cmulf(a, dinv[j]);
            loc[j][t] = tj;
            T[(size_t)j * BAP + r] = tj;
            float2 vj = v[j];
            xacc.x -= tj.x*vj.x - tj.y*vj.y;
            xacc.y -= tj.x*vj.y + tj.y*vj.x;
        }
        xd[r] = xacc;
    } else {
        int c = blockIdx.x * 64 + t;
        for (int j = 0; j < 64; ++j) src[j][t] = G[(size_t)(p0+j)*BAP + c];
        for (int j = 0; j < 64; ++j) {
            float2 a = src[j][t];
            for (int k = 0; k < j; ++k) {
                float2 tjk = Tp[j*64 + k];
                float2 lk = loc[k][t];
                a.x -= lk.x*tjk.x - lk.y*tjk.y;
                a.y -= lk.x*tjk.y + lk.y*tjk.x;
            }
            loc[j][t] = a;
            W[(size_t)j * BAP + c] = a;
        }
    }
}

// ---------------- trailing update: G -= T*W ----------------
__global__ __launch_bounds__(256) void trailing_update(float2* __restrict__ G,
                                                       const float2* __restrict__ T, const float2* __restrict__ W) {
    __shared__ float2 Tb[64][64];
    __shared__ float2 Wb[64][64];
    int t = threadIdx.x;
    int cx = blockIdx.x * 64, ry = blockIdx.y * 64;
    #pragma unroll
    for (int r = 0; r < 16; ++r) {
        int e = t + 256*r;
        int k = e >> 6, x = e & 63;
        Tb[k][x] = T[(size_t)k * BAP + ry + x];
        Wb[k][x] = W[(size_t)k * BAP + cx + x];
    }
    __syncthreads();
    int ti = t >> 4, tc = t & 15;
    float2 acc[4][4];
    #pragma unroll
    for (int a = 0; a < 4; ++a)
        #pragma unroll
        for (int b = 0; b < 4; ++b) acc[a][b] = make_float2(0.f, 0.f);
    for (int k = 0; k < 64; ++k) {
        float2 av[4], bv[4];
        #pragma unroll
        for (int s = 0; s < 4; ++s) { av[s] = Tb[k][ti*4+s]; bv[s] = Wb[k][tc*4+s]; }
        #pragma unroll
        for (int si = 0; si < 4; ++si)
            #pragma unroll
            for (int sc = 0; sc < 4; ++sc) {
                acc[si][sc].x += av[si].x*bv[sc].x - av[si].y*bv[sc].y;
                acc[si][sc].y += av[si].x*bv[sc].y + av[si].y*bv[sc].x;
            }
    }
    #pragma unroll
    for (int si = 0; si < 4; ++si) {
        size_t row = (size_t)(ry + ti*4 + si);
        float2* gp = G + row * BAP + cx + tc*4;
        #pragma unroll
        for (int sc = 0; sc < 4; ++sc) {
            float2 gg = gp[sc];
            gg.x -= acc[si][sc].x;
            gg.y -= acc[si][sc].y;
            gp[sc] = gg;
        }
    }
}

// ---------------- finalize: out[b][a] = xd[j]/G[j][j], j = b*50+(49-a) ----------------
// OUTPUT: f32 REAL plane at out[0..1999] (complex64 -> astype(f32) drops imag).
// Imag plane written at out[2000..3999] only if the buffer has room.
__global__ __launch_bounds__(256) void finalize_k(const float2* __restrict__ G, const float2* __restrict__ xd,
                                                  float* __restrict__ out, int out_size) {
    int o = blockIdx.x * 256 + threadIdx.x;
    if (o >= 2000) return;
    int b = o / 50, a = o % 50;
    int j = b * 50 + (49 - a);
    float2 x = xd[j];
    float2 g = G[(size_t)j * BAP + j];
    float den = 1.0f / (g.x*g.x + g.y*g.y);
    float re = (x.x*g.x + x.y*g.y) * den;
    float im = (x.y*g.x - x.x*g.y) * den;
    out[o] = re;
    if (out_size >= 4000) out[2000 + o] = im;
}

extern "C" void kernel_launch(void* const* d_in, const int* in_sizes, int n_in,
                              void* d_out, int out_size, void* d_ws, size_t ws_size,
                              hipStream_t stream) {
    const float* sar = (const float*)d_in[0];
    const int*   py  = (const int*)d_in[1];
    float* out = (float*)d_out;
    char* w = (char*)d_ws;
    size_t off = 0;
    auto take = [&](size_t sz) -> char* { char* p = w + off; off += (sz + 255) & ~(size_t)255; return p; };

    float*  R0 = (float*)take((size_t)BAP*BAP*4);
    float*  R1 = (float*)take((size_t)BAP*BAP*4);
    float*  P0 = (float*)take((size_t)BAP*BAP*4);
    float*  P1 = (float*)take((size_t)BAP*BAP*4);
    float2* G  = (float2*)take((size_t)BAP*BAP*8);
    float2* T  = (float2*)take((size_t)64*BAP*8);
    float2* W  = (float2*)take((size_t)64*BAP*8);
    float2* xd = (float2*)take((size_t)BAP*8);
    float*  ay = (float*)take((size_t)KPADMAX*4);
    float*  ax = (float*)take((size_t)KPADMAX*4);
    float*  rd = (float*)take((size_t)KPADMAX*4);
    float2* Tp = (float2*)take(64*64*8);
    float2* Wp = (float2*)take(64*64*8);
    float2* dinv = (float2*)take(64*8);
    float2* vv   = (float2*)take(64*8);

    size_t avail = (ws_size > off + 4096) ? (ws_size - off - 4096) : 0;
    long long Kc = (long long)(avail / 8192) & ~2047LL;   // 8192 B per k (2 f16 matrices x 2048 rows)
    if (Kc > KPADMAX) Kc = KPADMAX;
    if (Kc < 2048) Kc = 2048;
    _Float16* C = (_Float16*)take((size_t)BAP * Kc * 2);
    _Float16* S = (_Float16*)take((size_t)BAP * Kc * 2);
    int nch = (int)((KKTOT + Kc - 1) / Kc);
    int kiters = (int)(Kc / 64);

    hipMemsetAsync(R0, 0, (size_t)BAP*BAP*4*4, stream);  // R0,R1,P0,P1 contiguous

    decode_k<<<dim3(391), dim3(256), 0, stream>>>(sar, py, ay, ax, rd);
    xd_init<<<dim3(BAP), dim3(256), 0, stream>>>(ay, ax, rd, xd);

    for (int c0 = 0; c0 < nch; ++c0) {
        gen_cs<<<dim3((unsigned)(Kc/2048), BAP), dim3(256), 0, stream>>>(C, S, ay, ax, (int)(c0*Kc), (int)Kc);
        gemm_gram<<<dim3(16,16,2), dim3(256), 0, stream>>>(C, C, S, S, R0, R1, kiters, (int)Kc, 2);
        gemm_gram<<<dim3(16,16,2), dim3(256), 0, stream>>>(C, S, C, S, P0, P1, kiters, (int)Kc, 1);
    }
    build_G<<<dim3(8, BAP), dim3(256), 0, stream>>>(R0, R1, P0, P1, G);

    for (int p = 0; p < 32; ++p) {
        int p0 = p * 64;
        panel_factor<<<dim3(1), dim3(256), 0, stream>>>(G, xd, Tp, Wp, dinv, vv, p0);
        panel_TW<<<dim3(32, 2), dim3(64), 0, stream>>>(G, xd, T, W, Tp, Wp, dinv, vv, p0);
        trailing_update<<<dim3(32, 32), dim3(256), 0, stream>>>(G, T, W);
    }
    finalize_k<<<dim3(8), dim3(256), 0, stream>>>(G, xd, out, out_size);
}

// Round 8
// 10664.724 us; speedup vs baseline: 1.0198x; 1.0198x over previous
//
#include <hip/hip_runtime.h>
#include <hip/hip_bf16.h>
#include <stdint.h>

#define KKTOT 100000
#define BAP   2048
#define KPADMAX 100352   // 49*2048

typedef _Float16 f16x8 __attribute__((ext_vector_type(8)));
typedef float    f32x4 __attribute__((ext_vector_type(4)));

// ---- constants (match reference f32 arithmetic) ----
__device__ __constant__ float KCf  = (float)(4.0 * 3.14159265358979323846 * 77.0e9 / 299792458.0);
__device__ __constant__ float I2PA = (float)(0.15915494309189534940823);
__device__ __constant__ float I2PB = (float)(0.15915494309189534940823 - (double)(float)(0.15915494309189534940823));

__device__ __forceinline__ float phase_frac(float dy, float dxx) {
    float d2 = fmaf(dy, dy, fmaf(dxx, dxx, 0.09f));
    float ph = KCf * sqrtf(d2);
    float h  = ph * I2PA;
    float l  = fmaf(ph, I2PA, -h);
    l = fmaf(ph, I2PB, l);
    return (h - floorf(h)) + l;                  // revolutions
}

__device__ __forceinline__ void gload16(const void* g, void* l) {
    __builtin_amdgcn_global_load_lds(
        (__attribute__((address_space(1))) void*)(uintptr_t)g,
        (__attribute__((address_space(3))) void*)(uint32_t)(uintptr_t)l,
        16, 0, 0);
}

__device__ __forceinline__ float2 cmulf(float2 a, float2 b) {
    return make_float2(a.x*b.x - a.y*b.y, a.x*b.y + a.y*b.x);
}

// ---------------- decode py (int32) ----------------
__global__ __launch_bounds__(256) void decode_k(const float* __restrict__ sar, const int* __restrict__ py,
                                                float* __restrict__ ay, float* __restrict__ ax, float* __restrict__ rd) {
    int i = blockIdx.x * 256 + threadIdx.x;
    if (i >= KKTOT) return;
    int p = py[i];
    int iy = p & 511, ix = p >> 9;
    ay[i] = ((float)iy + 0.5f - 256.0f) * 1e-3f;
    ax[i] = ((float)ix + 0.5f - 256.0f) * 1e-3f;
    rd[i] = sar[p];
}

// ---------------- generate C=cos, S=sin as f16, layout [2048][Kc] ----------------
__global__ __launch_bounds__(256) void gen_cs(_Float16* __restrict__ C, _Float16* __restrict__ S,
                                              const float* __restrict__ ay, const float* __restrict__ ax,
                                              int k0, int Kc) {
    int j = blockIdx.y;
    long long kk = ((long long)blockIdx.x * 256 + threadIdx.x) * 8;
    size_t o = (size_t)j * Kc + kk;
    long long kg = (long long)k0 + kk;
    f16x8 cv, sv;
    if (j < 2000 && kg < KKTOT) {
        int jy = j % 40, jx = j / 40;
        float why = ((float)jy * (200.0f/39.0f) - 100.0f) * 1e-3f;   // wh2[jy]
        float whx = ((float)jx * (200.0f/49.0f) - 100.0f) * 1e-3f;   // wh1[jx]
        float4 a0 = *(const float4*)(ay + kg);
        float4 a1 = *(const float4*)(ay + kg + 4);
        float4 b0 = *(const float4*)(ax + kg);
        float4 b1 = *(const float4*)(ax + kg + 4);
        float ayv[8] = {a0.x,a0.y,a0.z,a0.w,a1.x,a1.y,a1.z,a1.w};
        float axv[8] = {b0.x,b0.y,b0.z,b0.w,b1.x,b1.y,b1.z,b1.w};
        #pragma unroll
        for (int e = 0; e < 8; ++e) {
            float fr = phase_frac(ayv[e]-why, axv[e]-whx);
            cv[e] = (_Float16)__builtin_amdgcn_cosf(fr);
            sv[e] = (_Float16)__builtin_amdgcn_sinf(fr);
        }
    } else {
        #pragma unroll
        for (int e = 0; e < 8; ++e) { cv[e] = (_Float16)0.f; sv[e] = (_Float16)0.f; }
    }
    *(f16x8*)(C + o) = cv;
    *(f16x8*)(S + o) = sv;
}

// ---------------- FUSED MFMA Gram GEMM ----------------
// R[m][n] += sum_k C[m][k]C[n][k] + S[m][k]S[n][k]   (CtC + StS)
// P[m][n] += sum_k C[m][k]S[n][k]                    (CtS)
// One kernel, 4 streams (Ca,Sa,Cb,Sb) instead of 6 across two dispatches.
__global__ __launch_bounds__(256) void gemm_fused(const _Float16* __restrict__ C, const _Float16* __restrict__ S,
                                                  float* __restrict__ R0, float* __restrict__ R1,
                                                  float* __restrict__ P0, float* __restrict__ P1,
                                                  int kiters, int kstride) {
    __shared__ _Float16 ldsCa[8192];  // [128 j][64 k] swizzled, 16KB each
    __shared__ _Float16 ldsSa[8192];
    __shared__ _Float16 ldsCb[8192];
    __shared__ _Float16 ldsSb[8192];
    const int t = threadIdx.x;
    const int w = t >> 6;
    const int lane = t & 63;
    const int mi = blockIdx.x, ni = blockIdx.y, z = blockIdx.z;
    float* Rout = z ? R1 : R0;
    float* Pout = z ? P1 : P0;

    f32x4 accR[4][4], accP[4][4];
    #pragma unroll
    for (int a = 0; a < 4; ++a)
        #pragma unroll
        for (int b = 0; b < 4; ++b) { accR[a][b] = (f32x4){0.f,0.f,0.f,0.f}; accP[a][b] = (f32x4){0.f,0.f,0.f,0.f}; }

    size_t aoff[4], boff[4];
    #pragma unroll
    for (int r = 0; r < 4; ++r) {
        int c = r * 256 + t;
        int jl = c >> 3;
        int ks = (c & 7) ^ (jl & 7);
        aoff[r] = (size_t)(mi*128 + jl) * kstride + ks*8;
        boff[r] = (size_t)(ni*128 + jl) * kstride + ks*8;
    }
    const int wm = w & 1, wn = w >> 1;
    const int q = lane >> 4, lm = lane & 15;
    const int ajl = wm*64 + lm;
    const int aoffl = (ajl*8 + (q ^ (ajl & 7))) * 16;
    const int bjl = wn*64 + lm;
    const int boffl = (bjl*8 + (q ^ (bjl & 7))) * 16;

    const int kh = kiters >> 1;
    for (int kt = z*kh; kt < (z+1)*kh; ++kt) {
        __syncthreads();
        const _Float16* gc = C + (size_t)kt * 64;
        const _Float16* gs = S + (size_t)kt * 64;
        #pragma unroll
        for (int r = 0; r < 4; ++r) {
            size_t dst = (size_t)(r*256 + w*64)*16;
            gload16(gc + aoff[r], (char*)ldsCa + dst);
            gload16(gs + aoff[r], (char*)ldsSa + dst);
            gload16(gc + boff[r], (char*)ldsCb + dst);
            gload16(gs + boff[r], (char*)ldsSb + dst);
        }
        __syncthreads();
        #pragma unroll
        for (int ks = 0; ks < 2; ++ks) {
            f16x8 bfC[4], bfS[4];
            #pragma unroll
            for (int nt = 0; nt < 4; ++nt) {
                bfC[nt] = *(const f16x8*)((const char*)ldsCb + ((boffl ^ (ks*64)) + nt*2048));
                bfS[nt] = *(const f16x8*)((const char*)ldsSb + ((boffl ^ (ks*64)) + nt*2048));
            }
            #pragma unroll
            for (int mt = 0; mt < 4; ++mt) {
                f16x8 afC = *(const f16x8*)((const char*)ldsCa + ((aoffl ^ (ks*64)) + mt*2048));
                f16x8 afS = *(const f16x8*)((const char*)ldsSa + ((aoffl ^ (ks*64)) + mt*2048));
                #pragma unroll
                for (int nt = 0; nt < 4; ++nt) {
                    accR[mt][nt] = __builtin_amdgcn_mfma_f32_16x16x32_f16(afC, bfC[nt], accR[mt][nt], 0, 0, 0);
                    accR[mt][nt] = __builtin_amdgcn_mfma_f32_16x16x32_f16(afS, bfS[nt], accR[mt][nt], 0, 0, 0);
                    accP[mt][nt] = __builtin_amdgcn_mfma_f32_16x16x32_f16(afC, bfS[nt], accP[mt][nt], 0, 0, 0);
                }
            }
        }
    }
    #pragma unroll
    for (int mt = 0; mt < 4; ++mt) {
        #pragma unroll
        for (int nt = 0; nt < 4; ++nt) {
            int row0 = mi*128 + wm*64 + mt*16 + q*4;
            int col  = ni*128 + wn*64 + nt*16 + lm;
            float* rp = Rout + (size_t)row0 * BAP + col;
            float* pp = Pout + (size_t)row0 * BAP + col;
            #pragma unroll
            for (int rr = 0; rr < 4; ++rr) {
                rp[(size_t)rr * BAP] += accR[mt][nt][rr];
                pp[(size_t)rr * BAP] += accP[mt][nt][rr];
            }
        }
    }
}

// ---------------- xd = DI * Hp^H rd ----------------
__global__ __launch_bounds__(256) void xd_init(const float* __restrict__ ay, const float* __restrict__ ax,
                                               const float* __restrict__ rd, float2* __restrict__ xd) {
    int j = blockIdx.x;
    int t = threadIdx.x;
    __shared__ float redr[256], redi[256];
    if (j >= 2000) { if (t == 0) xd[j] = make_float2(0.f, 0.f); return; }
    int jy = j % 40, jx = j / 40;
    float why = ((float)jy * (200.0f/39.0f) - 100.0f) * 1e-3f;
    float whx = ((float)jx * (200.0f/49.0f) - 100.0f) * 1e-3f;
    float sr = 0.f, si = 0.f;
    for (int i = t; i < KKTOT; i += 256) {
        float fr = phase_frac(ay[i]-why, ax[i]-whx);
        float r = rd[i];
        sr = fmaf(r, __builtin_amdgcn_cosf(fr), sr);
        si = fmaf(r, __builtin_amdgcn_sinf(fr), si);
    }
    redr[t] = sr; redi[t] = si;
    __syncthreads();
    for (int s2 = 128; s2 > 0; s2 >>= 1) {
        if (t < s2) { redr[t] += redr[t+s2]; redi[t] += redi[t+s2]; }
        __syncthreads();
    }
    if (t == 0) xd[j] = make_float2(0.01f * redr[0], -0.01f * redi[0]);
}

// ---------------- G = DI*(R, P - P^T) ----------------
__global__ __launch_bounds__(256) void build_G(const float* __restrict__ R0, const float* __restrict__ R1,
                                               const float* __restrict__ P0, const float* __restrict__ P1,
                                               float2* __restrict__ G) {
    int m = blockIdx.y;
    int n = blockIdx.x * 256 + threadIdx.x;
    size_t mn = (size_t)m * BAP + n, nm = (size_t)n * BAP + m;
    float re = 0.01f * (R0[mn] + R1[mn]);
    float im = 0.01f * ((P0[mn] + P1[mn]) - (P0[nm] + P1[nm]));
    G[mn] = make_float2(re, im);
}

// ---------------- panel factorization (64x64 sequential core) — validated vs brute force ----------------
__global__ __launch_bounds__(256) void panel_factor(const float2* __restrict__ G, const float2* __restrict__ xd,
                                                    float2* __restrict__ Tp, float2* __restrict__ Wp,
                                                    float2* __restrict__ dinv, float2* __restrict__ v, int p0) {
    __shared__ float2 Rcm[64*65];   // Rcm[c*65+i] = R[i][c]
    __shared__ float2 rowj[64];
    __shared__ float2 xdp[64];
    int t = threadIdx.x;
    int i = t & 63, cg = t >> 6;
    int cbase = cg * 16;
    #pragma unroll
    for (int r = 0; r < 16; ++r) {
        int e = t + 256*r;
        int ci = e & 63, ri = e >> 6;
        Rcm[ci*65 + ri] = G[(size_t)(p0+ri)*BAP + p0 + ci];
    }
    if (cg == 0) xdp[i] = xd[p0 + i];
    __syncthreads();
    for (int j = 0; j < 64; ++j) {
        float2 pr = Rcm[j*65 + j];
        float dr = 1.0f + pr.x, dii = pr.y;
        float idn = 1.0f / (dr*dr + dii*dii);
        float2 dv = make_float2(dr*idn, -dii*idn);
        float2 col = Rcm[j*65 + i];
        float2 tp = cmulf(col, dv);
        float2 vj = xdp[j];
        if (i == j) {
            for (int c = cbase; c < cbase+16; ++c) {
                float2 rv = Rcm[c*65 + j];
                rowj[c] = rv;
                Wp[j*64 + c] = rv;
            }
            if (cg == 0) { dinv[j] = dv; v[j] = vj; }
        }
        __syncthreads();
        for (int c = cbase; c < cbase+16; ++c) {
            float2 rj = rowj[c];
            float2 cur = Rcm[c*65 + i];
            cur.x -= tp.x*rj.x - tp.y*rj.y;
            cur.y -= tp.x*rj.y + tp.y*rj.x;
            Rcm[c*65 + i] = cur;
        }
        if (cg == 0) {
            Tp[i*64 + j] = tp;
            float2 xi = xdp[i];
            xi.x -= tp.x*vj.x - tp.y*vj.y;
            xi.y -= tp.x*vj.y + tp.y*vj.x;
            xdp[i] = xi;
        }
        __syncthreads();
    }
}

// ---------------- T (2048x64) / W (64x2048) recurrences; role 0 also updates xd ----------------
__global__ __launch_bounds__(64) void panel_TW(const float2* __restrict__ G, float2* __restrict__ xd,
                                               float2* __restrict__ T, float2* __restrict__ W,
                                               const float2* __restrict__ Tp, const float2* __restrict__ Wp,
                                               const float2* __restrict__ dinv, const float2* __restrict__ v, int p0) {
    __shared__ float2 src[64][64];
    __shared__ float2 loc[64][64];
    int t = threadIdx.x;
    if (blockIdx.y == 0) {
        int r = blockIdx.x * 64 + t;
        const float4* gp = (const float4*)(G + (size_t)r * BAP + p0);
        #pragma unroll
        for (int jj = 0; jj < 32; ++jj) {
            float4 qd = gp[jj];
            src[2*jj][t]   = make_float2(qd.x, qd.y);
            src[2*jj+1][t] = make_float2(qd.z, qd.w);
        }
        float2 xacc = xd[r];
        for (int j = 0; j < 64; ++j) {
            float2 a = src[j][t];
            for (int k = 0; k < j; ++k) {
                float2 wkj = Wp[k*64 + j];
                float2 lk = loc[k][t];
                a.x -= lk.x*wkj.x - lk.y*wkj.y;
                a.y -= lk.x*wkj.y + lk.y*wkj.x;
            }
            float2 tj = cmulf(a, dinv[j]);
            loc[j][t] = tj;
            T[(size_t)j * BAP + r] = tj;
            float2 vj = v[j];
            xacc.x -= tj.x*vj.x - tj.y*vj.y;
            xacc.y -= tj.x*vj.y + tj.y*vj.x;
        }
        xd[r] = xacc;
    } else {
        int c = blockIdx.x * 64 + t;
        for (int j = 0; j < 64; ++j) src[j][t] = G[(size_t)(p0+j)*BAP + c];
        for (int j = 0; j < 64; ++j) {
            float2 a = src[j][t];
            for (int k = 0; k < j; ++k) {
                float2 tjk = Tp[j*64 + k];
                float2 lk = loc[k][t];
                a.x -= lk.x*tjk.x - lk.y*tjk.y;
                a.y -= lk.x*tjk.y + lk.y*tjk.x;
            }
            loc[j][t] = a;
            W[(size_t)j * BAP + c] = a;
        }
    }
}

// ---------------- trailing update: G -= T*W (128x64 tiles, 8x4 per thread) ----------------
__global__ __launch_bounds__(256) void trailing_update(float2* __restrict__ G,
                                                       const float2* __restrict__ T, const float2* __restrict__ W) {
    __shared__ float2 Tb[16][128];   // [k][row] 16 KB
    __shared__ float2 Wb[16][64];    // [k][col] 8 KB
    int t = threadIdx.x;
    int cx = blockIdx.x * 64, ry = blockIdx.y * 128;
    int rq = t >> 4, cq = t & 15;    // row base, col base
    float2 acc[8][4];
    #pragma unroll
    for (int s = 0; s < 8; ++s)
        #pragma unroll
        for (int u = 0; u < 4; ++u) acc[s][u] = make_float2(0.f, 0.f);

    for (int k0 = 0; k0 < 64; k0 += 16) {
        __syncthreads();
        // stage Tb: 1024 float4 (= 16 k-rows x 64 float4)
        #pragma unroll
        for (int r = 0; r < 4; ++r) {
            int e = t + 256*r;
            int k = e >> 6, x4 = e & 63;
            *(float4*)&Tb[k][x4*2] = *(const float4*)(T + (size_t)(k0+k) * BAP + ry + x4*2);
        }
        // stage Wb: 512 float4
        #pragma unroll
        for (int r = 0; r < 2; ++r) {
            int e = t + 256*r;
            int k = e >> 5, x4 = e & 31;
            *(float4*)&Wb[k][x4*2] = *(const float4*)(W + (size_t)(k0+k) * BAP + cx + x4*2);
        }
        __syncthreads();
        #pragma unroll
        for (int k = 0; k < 16; ++k) {
            float2 av[8], bv[4];
            #pragma unroll
            for (int s = 0; s < 8; ++s) av[s] = Tb[k][rq + 16*s];
            #pragma unroll
            for (int u = 0; u < 4; ++u) bv[u] = Wb[k][cq + 16*u];
            #pragma unroll
            for (int s = 0; s < 8; ++s)
                #pragma unroll
                for (int u = 0; u < 4; ++u) {
                    acc[s][u].x = fmaf(av[s].x, bv[u].x, fmaf(-av[s].y, bv[u].y, acc[s][u].x));
                    acc[s][u].y = fmaf(av[s].x, bv[u].y, fmaf( av[s].y, bv[u].x, acc[s][u].y));
                }
        }
    }
    #pragma unroll
    for (int s = 0; s < 8; ++s) {
        float2* gp = G + (size_t)(ry + rq + 16*s) * BAP + cx + cq;
        #pragma unroll
        for (int u = 0; u < 4; ++u) {
            float2 gg = gp[16*u];
            gg.x -= acc[s][u].x;
            gg.y -= acc[s][u].y;
            gp[16*u] = gg;
        }
    }
}

// ---------------- finalize: out[b][a] = Re(xd[j]/G[j][j]), j = b*50+(49-a); f32 real plane ----------------
__global__ __launch_bounds__(256) void finalize_k(const float2* __restrict__ G, const float2* __restrict__ xd,
                                                  float* __restrict__ out, int out_size) {
    int o = blockIdx.x * 256 + threadIdx.x;
    if (o >= 2000) return;
    int b = o / 50, a = o % 50;
    int j = b * 50 + (49 - a);
    float2 x = xd[j];
    float2 g = G[(size_t)j * BAP + j];
    float den = 1.0f / (g.x*g.x + g.y*g.y);
    float re = (x.x*g.x + x.y*g.y) * den;
    float im = (x.y*g.x - x.x*g.y) * den;
    out[o] = re;
    if (out_size >= 4000) out[2000 + o] = im;
}

extern "C" void kernel_launch(void* const* d_in, const int* in_sizes, int n_in,
                              void* d_out, int out_size, void* d_ws, size_t ws_size,
                              hipStream_t stream) {
    const float* sar = (const float*)d_in[0];
    const int*   py  = (const int*)d_in[1];
    float* out = (float*)d_out;
    char* w = (char*)d_ws;
    size_t off = 0;
    auto take = [&](size_t sz) -> char* { char* p = w + off; off += (sz + 255) & ~(size_t)255; return p; };

    float*  R0 = (float*)take((size_t)BAP*BAP*4);
    float*  R1 = (float*)take((size_t)BAP*BAP*4);
    float*  P0 = (float*)take((size_t)BAP*BAP*4);
    float*  P1 = (float*)take((size_t)BAP*BAP*4);
    float2* G  = (float2*)take((size_t)BAP*BAP*8);
    float2* T  = (float2*)take((size_t)64*BAP*8);
    float2* W  = (float2*)take((size_t)64*BAP*8);
    float2* xd = (float2*)take((size_t)BAP*8);
    float*  ay = (float*)take((size_t)KPADMAX*4);
    float*  ax = (float*)take((size_t)KPADMAX*4);
    float*  rd = (float*)take((size_t)KPADMAX*4);
    float2* Tp = (float2*)take(64*64*8);
    float2* Wp = (float2*)take(64*64*8);
    float2* dinv = (float2*)take(64*8);
    float2* vv   = (float2*)take(64*8);

    size_t avail = (ws_size > off + 4096) ? (ws_size - off - 4096) : 0;
    long long Kc = (long long)(avail / 8192) & ~2047LL;   // 8192 B per k (2 f16 matrices x 2048 rows)
    if (Kc > KPADMAX) Kc = KPADMAX;
    if (Kc < 2048) Kc = 2048;
    _Float16* C = (_Float16*)take((size_t)BAP * Kc * 2);
    _Float16* S = (_Float16*)take((size_t)BAP * Kc * 2);
    int nch = (int)((KKTOT + Kc - 1) / Kc);
    int kiters = (int)(Kc / 64);

    hipMemsetAsync(R0, 0, (size_t)BAP*BAP*4*4, stream);  // R0,R1,P0,P1 contiguous

    decode_k<<<dim3(391), dim3(256), 0, stream>>>(sar, py, ay, ax, rd);
    xd_init<<<dim3(BAP), dim3(256), 0, stream>>>(ay, ax, rd, xd);

    for (int c0 = 0; c0 < nch; ++c0) {
        gen_cs<<<dim3((unsigned)(Kc/2048), BAP), dim3(256), 0, stream>>>(C, S, ay, ax, (int)(c0*Kc), (int)Kc);
        gemm_fused<<<dim3(16,16,2), dim3(256), 0, stream>>>(C, S, R0, R1, P0, P1, kiters, (int)Kc);
    }
    build_G<<<dim3(8, BAP), dim3(256), 0, stream>>>(R0, R1, P0, P1, G);

    for (int p = 0; p < 32; ++p) {
        int p0 = p * 64;
        panel_factor<<<dim3(1), dim3(256), 0, stream>>>(G, xd, Tp, Wp, dinv, vv, p0);
        panel_TW<<<dim3(32, 2), dim3(64), 0, stream>>>(G, xd, T, W, Tp, Wp, dinv, vv, p0);
        trailing_update<<<dim3(32, 16), dim3(256), 0, stream>>>(G, T, W);
    }
    finalize_k<<<dim3(8), dim3(256), 0, stream>>>(G, xd, out, out_size);
}

// Round 9
// 9503.577 us; speedup vs baseline: 1.1444x; 1.1222x over previous
//
#include <hip/hip_runtime.h>
#include <hip/hip_bf16.h>
#include <stdint.h>

#define KKTOT 100000
#define BAP   2048
#define KPADMAX 100352   // 49*2048

typedef _Float16 f16x8 __attribute__((ext_vector_type(8)));
typedef float    f32x4 __attribute__((ext_vector_type(4)));

// ---- constants (match reference f32 arithmetic) ----
__device__ __constant__ float KCf  = (float)(4.0 * 3.14159265358979323846 * 77.0e9 / 299792458.0);
__device__ __constant__ float I2PA = (float)(0.15915494309189534940823);
__device__ __constant__ float I2PB = (float)(0.15915494309189534940823 - (double)(float)(0.15915494309189534940823));

__device__ __forceinline__ float phase_frac(float dy, float dxx) {
    float d2 = fmaf(dy, dy, fmaf(dxx, dxx, 0.09f));
    float ph = KCf * sqrtf(d2);
    float h  = ph * I2PA;
    float l  = fmaf(ph, I2PA, -h);
    l = fmaf(ph, I2PB, l);
    return (h - floorf(h)) + l;                  // revolutions
}

__device__ __forceinline__ void gload16(const void* g, void* l) {
    __builtin_amdgcn_global_load_lds(
        (__attribute__((address_space(1))) void*)(uintptr_t)g,
        (__attribute__((address_space(3))) void*)(uint32_t)(uintptr_t)l,
        16, 0, 0);
}

__device__ __forceinline__ float2 cmulf(float2 a, float2 b) {
    return make_float2(a.x*b.x - a.y*b.y, a.x*b.y + a.y*b.x);
}

// ---------------- decode py (int32) ----------------
__global__ __launch_bounds__(256) void decode_k(const float* __restrict__ sar, const int* __restrict__ py,
                                                float* __restrict__ ay, float* __restrict__ ax, float* __restrict__ rd) {
    int i = blockIdx.x * 256 + threadIdx.x;
    if (i >= KKTOT) return;
    int p = py[i];
    int iy = p & 511, ix = p >> 9;
    ay[i] = ((float)iy + 0.5f - 256.0f) * 1e-3f;
    ax[i] = ((float)ix + 0.5f - 256.0f) * 1e-3f;
    rd[i] = sar[p];
}

// ---------------- generate C=cos, S=sin as f16, layout [2048][Kc] ----------------
__global__ __launch_bounds__(256) void gen_cs(_Float16* __restrict__ C, _Float16* __restrict__ S,
                                              const float* __restrict__ ay, const float* __restrict__ ax,
                                              int k0, int Kc) {
    int j = blockIdx.y;
    long long kk = ((long long)blockIdx.x * 256 + threadIdx.x) * 8;
    size_t o = (size_t)j * Kc + kk;
    long long kg = (long long)k0 + kk;
    f16x8 cv, sv;
    if (j < 2000 && kg < KKTOT) {
        int jy = j % 40, jx = j / 40;
        float why = ((float)jy * (200.0f/39.0f) - 100.0f) * 1e-3f;   // wh2[jy]
        float whx = ((float)jx * (200.0f/49.0f) - 100.0f) * 1e-3f;   // wh1[jx]
        float4 a0 = *(const float4*)(ay + kg);
        float4 a1 = *(const float4*)(ay + kg + 4);
        float4 b0 = *(const float4*)(ax + kg);
        float4 b1 = *(const float4*)(ax + kg + 4);
        float ayv[8] = {a0.x,a0.y,a0.z,a0.w,a1.x,a1.y,a1.z,a1.w};
        float axv[8] = {b0.x,b0.y,b0.z,b0.w,b1.x,b1.y,b1.z,b1.w};
        #pragma unroll
        for (int e = 0; e < 8; ++e) {
            float fr = phase_frac(ayv[e]-why, axv[e]-whx);
            cv[e] = (_Float16)__builtin_amdgcn_cosf(fr);
            sv[e] = (_Float16)__builtin_amdgcn_sinf(fr);
        }
    } else {
        #pragma unroll
        for (int e = 0; e < 8; ++e) { cv[e] = (_Float16)0.f; sv[e] = (_Float16)0.f; }
    }
    *(f16x8*)(C + o) = cv;
    *(f16x8*)(S + o) = sv;
}

// ---------------- UPPER-TRIANGLE fused Gram GEMM ----------------
// For tile (mi<=ni):
//   R[m][n]  += sum_k C[m]C[n] + S[m]S[n]
//   Pm[m][n] += sum_k C[m]S[n] - S[m]C[n]      (= P - P^T directly, via negated S A-fragment)
// Lower half reconstructed Hermitian in build_G_tile.
__global__ __launch_bounds__(256) void gemm_ut(const _Float16* __restrict__ C, const _Float16* __restrict__ S,
                                               float* __restrict__ R0, float* __restrict__ R1,
                                               float* __restrict__ Pm0, float* __restrict__ Pm1,
                                               int kiters, int kstride) {
    const int mi = blockIdx.x, ni = blockIdx.y, z = blockIdx.z;
    if (ni < mi) return;
    __shared__ _Float16 ldsCa[8192];  // [128 j][64 k] swizzled, 16KB each
    __shared__ _Float16 ldsSa[8192];
    __shared__ _Float16 ldsCb[8192];
    __shared__ _Float16 ldsSb[8192];
    const int t = threadIdx.x;
    const int w = t >> 6;
    const int lane = t & 63;
    float* Rout = z ? R1 : R0;
    float* Pout = z ? Pm1 : Pm0;

    f32x4 accR[4][4], accP[4][4];
    #pragma unroll
    for (int a = 0; a < 4; ++a)
        #pragma unroll
        for (int b = 0; b < 4; ++b) { accR[a][b] = (f32x4){0.f,0.f,0.f,0.f}; accP[a][b] = (f32x4){0.f,0.f,0.f,0.f}; }

    size_t aoff[4], boff[4];
    #pragma unroll
    for (int r = 0; r < 4; ++r) {
        int c = r * 256 + t;
        int jl = c >> 3;
        int ks = (c & 7) ^ (jl & 7);
        aoff[r] = (size_t)(mi*128 + jl) * kstride + ks*8;
        boff[r] = (size_t)(ni*128 + jl) * kstride + ks*8;
    }
    const int wm = w & 1, wn = w >> 1;
    const int q = lane >> 4, lm = lane & 15;
    const int ajl = wm*64 + lm;
    const int aoffl = (ajl*8 + (q ^ (ajl & 7))) * 16;
    const int bjl = wn*64 + lm;
    const int boffl = (bjl*8 + (q ^ (bjl & 7))) * 16;

    const int kh = kiters >> 1;
    for (int kt = z*kh; kt < (z+1)*kh; ++kt) {
        __syncthreads();
        const _Float16* gc = C + (size_t)kt * 64;
        const _Float16* gs = S + (size_t)kt * 64;
        #pragma unroll
        for (int r = 0; r < 4; ++r) {
            size_t dst = (size_t)(r*256 + w*64)*16;
            gload16(gc + aoff[r], (char*)ldsCa + dst);
            gload16(gs + aoff[r], (char*)ldsSa + dst);
            gload16(gc + boff[r], (char*)ldsCb + dst);
            gload16(gs + boff[r], (char*)ldsSb + dst);
        }
        __syncthreads();
        #pragma unroll
        for (int ks = 0; ks < 2; ++ks) {
            f16x8 bfC[4], bfS[4];
            #pragma unroll
            for (int nt = 0; nt < 4; ++nt) {
                bfC[nt] = *(const f16x8*)((const char*)ldsCb + ((boffl ^ (ks*64)) + nt*2048));
                bfS[nt] = *(const f16x8*)((const char*)ldsSb + ((boffl ^ (ks*64)) + nt*2048));
            }
            #pragma unroll
            for (int mt = 0; mt < 4; ++mt) {
                f16x8 afC = *(const f16x8*)((const char*)ldsCa + ((aoffl ^ (ks*64)) + mt*2048));
                f16x8 afS = *(const f16x8*)((const char*)ldsSa + ((aoffl ^ (ks*64)) + mt*2048));
                f16x8 nfS;
                #pragma unroll
                for (int e = 0; e < 8; ++e) nfS[e] = -afS[e];
                #pragma unroll
                for (int nt = 0; nt < 4; ++nt) {
                    accR[mt][nt] = __builtin_amdgcn_mfma_f32_16x16x32_f16(afC, bfC[nt], accR[mt][nt], 0, 0, 0);
                    accR[mt][nt] = __builtin_amdgcn_mfma_f32_16x16x32_f16(afS, bfS[nt], accR[mt][nt], 0, 0, 0);
                    accP[mt][nt] = __builtin_amdgcn_mfma_f32_16x16x32_f16(afC, bfS[nt], accP[mt][nt], 0, 0, 0);
                    accP[mt][nt] = __builtin_amdgcn_mfma_f32_16x16x32_f16(nfS, bfC[nt], accP[mt][nt], 0, 0, 0);
                }
            }
        }
    }
    #pragma unroll
    for (int mt = 0; mt < 4; ++mt) {
        #pragma unroll
        for (int nt = 0; nt < 4; ++nt) {
            int row0 = mi*128 + wm*64 + mt*16 + q*4;
            int col  = ni*128 + wn*64 + nt*16 + lm;
            float* rp = Rout + (size_t)row0 * BAP + col;
            float* pp = Pout + (size_t)row0 * BAP + col;
            #pragma unroll
            for (int rr = 0; rr < 4; ++rr) {
                rp[(size_t)rr * BAP] += accR[mt][nt][rr];
                pp[(size_t)rr * BAP] += accP[mt][nt][rr];
            }
        }
    }
}

// ---------------- xd = DI * Hp^H rd ----------------
__global__ __launch_bounds__(256) void xd_init(const float* __restrict__ ay, const float* __restrict__ ax,
                                               const float* __restrict__ rd, float2* __restrict__ xd) {
    int j = blockIdx.x;
    int t = threadIdx.x;
    __shared__ float redr[256], redi[256];
    if (j >= 2000) { if (t == 0) xd[j] = make_float2(0.f, 0.f); return; }
    int jy = j % 40, jx = j / 40;
    float why = ((float)jy * (200.0f/39.0f) - 100.0f) * 1e-3f;
    float whx = ((float)jx * (200.0f/49.0f) - 100.0f) * 1e-3f;
    float sr = 0.f, si = 0.f;
    for (int i = t; i < KKTOT; i += 256) {
        float fr = phase_frac(ay[i]-why, ax[i]-whx);
        float r = rd[i];
        sr = fmaf(r, __builtin_amdgcn_cosf(fr), sr);
        si = fmaf(r, __builtin_amdgcn_sinf(fr), si);
    }
    redr[t] = sr; redi[t] = si;
    __syncthreads();
    for (int s2 = 128; s2 > 0; s2 >>= 1) {
        if (t < s2) { redr[t] += redr[t+s2]; redi[t] += redi[t+s2]; }
        __syncthreads();
    }
    if (t == 0) xd[j] = make_float2(0.01f * redr[0], -0.01f * redi[0]);
}

// ---------------- build G from upper-tri planes, Hermitian mirror (tiled, coalesced) ----------------
__global__ __launch_bounds__(256) void build_G_tile(const float* __restrict__ R0, const float* __restrict__ R1,
                                                    const float* __restrict__ Pm0, const float* __restrict__ Pm1,
                                                    float2* __restrict__ G) {
    int ti = blockIdx.y, tj = blockIdx.x;
    if (tj < ti) return;
    __shared__ float2 tile[64][65];
    int t = threadIdx.x;
    #pragma unroll
    for (int r = 0; r < 16; ++r) {
        int e = t + 256*r;
        int lr = e >> 6, lc = e & 63;
        size_t mn = (size_t)(ti*64 + lr) * BAP + tj*64 + lc;
        float re = 0.01f * (R0[mn] + R1[mn]);
        float im = 0.01f * (Pm0[mn] + Pm1[mn]);
        G[mn] = make_float2(re, im);
        tile[lc][lr] = make_float2(re, -im);
    }
    if (tj == ti) return;
    __syncthreads();
    #pragma unroll
    for (int r = 0; r < 16; ++r) {
        int e = t + 256*r;
        int lr = e >> 6, lc = e & 63;
        G[(size_t)(tj*64 + lr) * BAP + ti*64 + lc] = tile[lr][lc];
    }
}

// ---------------- panel factorization (64x64 sequential core) — validated vs brute force ----------------
__global__ __launch_bounds__(256) void panel_factor(const float2* __restrict__ G, const float2* __restrict__ xd,
                                                    float2* __restrict__ Tp, float2* __restrict__ Wp,
                                                    float2* __restrict__ dinv, float2* __restrict__ v, int p0) {
    __shared__ float2 Rcm[64*65];   // Rcm[c*65+i] = R[i][c]
    __shared__ float2 rowj[64];
    __shared__ float2 xdp[64];
    int t = threadIdx.x;
    int i = t & 63, cg = t >> 6;
    int cbase = cg * 16;
    #pragma unroll
    for (int r = 0; r < 16; ++r) {
        int e = t + 256*r;
        int ci = e & 63, ri = e >> 6;
        Rcm[ci*65 + ri] = G[(size_t)(p0+ri)*BAP + p0 + ci];
    }
    if (cg == 0) xdp[i] = xd[p0 + i];
    __syncthreads();
    for (int j = 0; j < 64; ++j) {
        float2 pr = Rcm[j*65 + j];
        float dr = 1.0f + pr.x, dii = pr.y;
        float idn = 1.0f / (dr*dr + dii*dii);
        float2 dv = make_float2(dr*idn, -dii*idn);
        float2 col = Rcm[j*65 + i];
        float2 tp = cmulf(col, dv);
        float2 vj = xdp[j];
        if (i == j) {
            for (int c = cbase; c < cbase+16; ++c) {
                float2 rv = Rcm[c*65 + j];
                rowj[c] = rv;
                Wp[j*64 + c] = rv;
            }
            if (cg == 0) { dinv[j] = dv; v[j] = vj; }
        }
        __syncthreads();
        for (int c = cbase; c < cbase+16; ++c) {
            float2 rj = rowj[c];
            float2 cur = Rcm[c*65 + i];
            cur.x -= tp.x*rj.x - tp.y*rj.y;
            cur.y -= tp.x*rj.y + tp.y*rj.x;
            Rcm[c*65 + i] = cur;
        }
        if (cg == 0) {
            Tp[i*64 + j] = tp;
            float2 xi = xdp[i];
            xi.x -= tp.x*vj.x - tp.y*vj.y;
            xi.y -= tp.x*vj.y + tp.y*vj.x;
            xdp[i] = xi;
        }
        __syncthreads();
    }
}

// ---------------- T (2048x64) / W (64x2048) recurrences; panel mats preloaded to LDS ----------------
__global__ __launch_bounds__(64) void panel_TW(const float2* __restrict__ G, float2* __restrict__ xd,
                                               float2* __restrict__ T, float2* __restrict__ W,
                                               const float2* __restrict__ Tp, const float2* __restrict__ Wp,
                                               const float2* __restrict__ dinv, const float2* __restrict__ v, int p0) {
    __shared__ float2 src[64][64];
    __shared__ float2 loc[64][64];
    __shared__ float2 pan[64*64];    // Wp (role0) or Tp (role1)
    __shared__ float2 vloc[64], dloc[64];
    int t = threadIdx.x;
    const float2* psrc = (blockIdx.y == 0) ? Wp : Tp;
    for (int r = 0; r < 64; ++r) pan[r*64 + t] = psrc[r*64 + t];
    if (blockIdx.y == 0) { vloc[t] = v[t]; dloc[t] = dinv[t]; }
    if (blockIdx.y == 0) {
        int r = blockIdx.x * 64 + t;
        const float4* gp = (const float4*)(G + (size_t)r * BAP + p0);
        #pragma unroll
        for (int jj = 0; jj < 32; ++jj) {
            float4 qd = gp[jj];
            src[2*jj][t]   = make_float2(qd.x, qd.y);
            src[2*jj+1][t] = make_float2(qd.z, qd.w);
        }
        __syncthreads();
        float2 xacc = xd[r];
        for (int j = 0; j < 64; ++j) {
            float2 a = src[j][t];
            for (int k = 0; k < j; ++k) {
                float2 wkj = pan[k*64 + j];
                float2 lk = loc[k][t];
                a.x -= lk.x*wkj.x - lk.y*wkj.y;
                a.y -= lk.x*wkj.y + lk.y*wkj.x;
            }
            float2 tj = cmulf(a, dloc[j]);
            loc[j][t] = tj;
            T[(size_t)j * BAP + r] = tj;
            float2 vj = vloc[j];
            xacc.x -= tj.x*vj.x - tj.y*vj.y;
            xacc.y -= tj.x*vj.y + tj.y*vj.x;
        }
        xd[r] = xacc;
    } else {
        int c = blockIdx.x * 64 + t;
        for (int j = 0; j < 64; ++j) src[j][t] = G[(size_t)(p0+j)*BAP + c];
        __syncthreads();
        for (int j = 0; j < 64; ++j) {
            float2 a = src[j][t];
            for (int k = 0; k < j; ++k) {
                float2 tjk = pan[j*64 + k];
                float2 lk = loc[k][t];
                a.x -= lk.x*tjk.x - lk.y*tjk.y;
                a.y -= lk.x*tjk.y + lk.y*tjk.x;
            }
            loc[j][t] = a;
            W[(size_t)j * BAP + c] = a;
        }
    }
}

// ---------------- trailing update: G -= T*W (128x64 tiles, 8x4 per thread) ----------------
__global__ __launch_bounds__(256) void trailing_update(float2* __restrict__ G,
                                                       const float2* __restrict__ T, const float2* __restrict__ W) {
    __shared__ float2 Tb[16][128];   // [k][row] 16 KB
    __shared__ float2 Wb[16][64];    // [k][col] 8 KB
    int t = threadIdx.x;
    int cx = blockIdx.x * 64, ry = blockIdx.y * 128;
    int rq = t >> 4, cq = t & 15;
    float2 acc[8][4];
    #pragma unroll
    for (int s = 0; s < 8; ++s)
        #pragma unroll
        for (int u = 0; u < 4; ++u) acc[s][u] = make_float2(0.f, 0.f);

    for (int k0 = 0; k0 < 64; k0 += 16) {
        __syncthreads();
        #pragma unroll
        for (int r = 0; r < 4; ++r) {
            int e = t + 256*r;
            int k = e >> 6, x4 = e & 63;
            *(float4*)&Tb[k][x4*2] = *(const float4*)(T + (size_t)(k0+k) * BAP + ry + x4*2);
        }
        #pragma unroll
        for (int r = 0; r < 2; ++r) {
            int e = t + 256*r;
            int k = e >> 5, x4 = e & 31;
            *(float4*)&Wb[k][x4*2] = *(const float4*)(W + (size_t)(k0+k) * BAP + cx + x4*2);
        }
        __syncthreads();
        #pragma unroll
        for (int k = 0; k < 16; ++k) {
            float2 av[8], bv[4];
            #pragma unroll
            for (int s = 0; s < 8; ++s) av[s] = Tb[k][rq + 16*s];
            #pragma unroll
            for (int u = 0; u < 4; ++u) bv[u] = Wb[k][cq + 16*u];
            #pragma unroll
            for (int s = 0; s < 8; ++s)
                #pragma unroll
                for (int u = 0; u < 4; ++u) {
                    acc[s][u].x = fmaf(av[s].x, bv[u].x, fmaf(-av[s].y, bv[u].y, acc[s][u].x));
                    acc[s][u].y = fmaf(av[s].x, bv[u].y, fmaf( av[s].y, bv[u].x, acc[s][u].y));
                }
        }
    }
    #pragma unroll
    for (int s = 0; s < 8; ++s) {
        float2* gp = G + (size_t)(ry + rq + 16*s) * BAP + cx + cq;
        #pragma unroll
        for (int u = 0; u < 4; ++u) {
            float2 gg = gp[16*u];
            gg.x -= acc[s][u].x;
            gg.y -= acc[s][u].y;
            gp[16*u] = gg;
        }
    }
}

// ---------------- finalize: out[b][a] = Re(xd[j]/G[j][j]), j = b*50+(49-a); f32 real plane ----------------
__global__ __launch_bounds__(256) void finalize_k(const float2* __restrict__ G, const float2* __restrict__ xd,
                                                  float* __restrict__ out, int out_size) {
    int o = blockIdx.x * 256 + threadIdx.x;
    if (o >= 2000) return;
    int b = o / 50, a = o % 50;
    int j = b * 50 + (49 - a);
    float2 x = xd[j];
    float2 g = G[(size_t)j * BAP + j];
    float den = 1.0f / (g.x*g.x + g.y*g.y);
    float re = (x.x*g.x + x.y*g.y) * den;
    float im = (x.y*g.x - x.x*g.y) * den;
    out[o] = re;
    if (out_size >= 4000) out[2000 + o] = im;
}

extern "C" void kernel_launch(void* const* d_in, const int* in_sizes, int n_in,
                              void* d_out, int out_size, void* d_ws, size_t ws_size,
                              hipStream_t stream) {
    const float* sar = (const float*)d_in[0];
    const int*   py  = (const int*)d_in[1];
    float* out = (float*)d_out;
    char* w = (char*)d_ws;
    size_t off = 0;
    auto take = [&](size_t sz) -> char* { char* p = w + off; off += (sz + 255) & ~(size_t)255; return p; };

    float*  R0  = (float*)take((size_t)BAP*BAP*4);
    float*  R1  = (float*)take((size_t)BAP*BAP*4);
    float*  Pm0 = (float*)take((size_t)BAP*BAP*4);
    float*  Pm1 = (float*)take((size_t)BAP*BAP*4);
    float2* G  = (float2*)take((size_t)BAP*BAP*8);
    float2* T  = (float2*)take((size_t)64*BAP*8);
    float2* W  = (float2*)take((size_t)64*BAP*8);
    float2* xd = (float2*)take((size_t)BAP*8);
    float*  ay = (float*)take((size_t)KPADMAX*4);
    float*  ax = (float*)take((size_t)KPADMAX*4);
    float*  rd = (float*)take((size_t)KPADMAX*4);
    float2* Tp = (float2*)take(64*64*8);
    float2* Wp = (float2*)take(64*64*8);
    float2* dinv = (float2*)take(64*8);
    float2* vv   = (float2*)take(64*8);

    size_t avail = (ws_size > off + 4096) ? (ws_size - off - 4096) : 0;
    long long Kc = (long long)(avail / 8192) & ~2047LL;   // 8192 B per k (2 f16 matrices x 2048 rows)
    if (Kc > KPADMAX) Kc = KPADMAX;
    if (Kc < 2048) Kc = 2048;
    _Float16* C = (_Float16*)take((size_t)BAP * Kc * 2);
    _Float16* S = (_Float16*)take((size_t)BAP * Kc * 2);
    int nch = (int)((KKTOT + Kc - 1) / Kc);
    int kiters = (int)(Kc / 64);

    hipMemsetAsync(R0, 0, (size_t)BAP*BAP*4*4, stream);  // R0,R1,Pm0,Pm1 contiguous

    decode_k<<<dim3(391), dim3(256), 0, stream>>>(sar, py, ay, ax, rd);
    xd_init<<<dim3(BAP), dim3(256), 0, stream>>>(ay, ax, rd, xd);

    for (int c0 = 0; c0 < nch; ++c0) {
        gen_cs<<<dim3((unsigned)(Kc/2048), BAP), dim3(256), 0, stream>>>(C, S, ay, ax, (int)(c0*Kc), (int)Kc);
        gemm_ut<<<dim3(16,16,2), dim3(256), 0, stream>>>(C, S, R0, R1, Pm0, Pm1, kiters, (int)Kc);
    }
    build_G_tile<<<dim3(32, 32), dim3(256), 0, stream>>>(R0, R1, Pm0, Pm1, G);

    for (int p = 0; p < 32; ++p) {
        int p0 = p * 64;
        panel_factor<<<dim3(1), dim3(256), 0, stream>>>(G, xd, Tp, Wp, dinv, vv, p0);
        panel_TW<<<dim3(32, 2), dim3(64), 0, stream>>>(G, xd, T, W, Tp, Wp, dinv, vv, p0);
        trailing_update<<<dim3(32, 16), dim3(256), 0, stream>>>(G, T, W);
    }
    finalize_k<<<dim3(8), dim3(256), 0, stream>>>(G, xd, out, out_size);
}

// Round 10
// 8378.176 us; speedup vs baseline: 1.2981x; 1.1343x over previous
//
#include <hip/hip_runtime.h>
#include <hip/hip_bf16.h>
#include <stdint.h>

#define KKTOT 100000
#define BAP   2048
#define KPADMAX 100352   // 49*2048

typedef _Float16 f16x8 __attribute__((ext_vector_type(8)));
typedef float    f32x4 __attribute__((ext_vector_type(4)));

// ---- constants (match reference f32 arithmetic) ----
__device__ __constant__ float KCf  = (float)(4.0 * 3.14159265358979323846 * 77.0e9 / 299792458.0);
__device__ __constant__ float I2PA = (float)(0.15915494309189534940823);
__device__ __constant__ float I2PB = (float)(0.15915494309189534940823 - (double)(float)(0.15915494309189534940823));

__device__ __forceinline__ float phase_frac(float dy, float dxx) {
    float d2 = fmaf(dy, dy, fmaf(dxx, dxx, 0.09f));
    float ph = KCf * sqrtf(d2);
    float h  = ph * I2PA;
    float l  = fmaf(ph, I2PA, -h);
    l = fmaf(ph, I2PB, l);
    return (h - floorf(h)) + l;                  // revolutions
}

__device__ __forceinline__ void gload16(const void* g, void* l) {
    __builtin_amdgcn_global_load_lds(
        (__attribute__((address_space(1))) void*)(uintptr_t)g,
        (__attribute__((address_space(3))) void*)(uint32_t)(uintptr_t)l,
        16, 0, 0);
}

__device__ __forceinline__ float2 cmulf(float2 a, float2 b) {
    return make_float2(a.x*b.x - a.y*b.y, a.x*b.y + a.y*b.x);
}

// ---------------- decode py (int32) ----------------
__global__ __launch_bounds__(256) void decode_k(const float* __restrict__ sar, const int* __restrict__ py,
                                                float* __restrict__ ay, float* __restrict__ ax, float* __restrict__ rd) {
    int i = blockIdx.x * 256 + threadIdx.x;
    if (i >= KKTOT) return;
    int p = py[i];
    int iy = p & 511, ix = p >> 9;
    ay[i] = ((float)iy + 0.5f - 256.0f) * 1e-3f;
    ax[i] = ((float)ix + 0.5f - 256.0f) * 1e-3f;
    rd[i] = sar[p];
}

// ---------------- generate C=cos, S=sin as f16, layout [2048][Kc] ----------------
__global__ __launch_bounds__(256) void gen_cs(_Float16* __restrict__ C, _Float16* __restrict__ S,
                                              const float* __restrict__ ay, const float* __restrict__ ax,
                                              int k0, int Kc) {
    int j = blockIdx.y;
    long long kk = ((long long)blockIdx.x * 256 + threadIdx.x) * 8;
    size_t o = (size_t)j * Kc + kk;
    long long kg = (long long)k0 + kk;
    f16x8 cv, sv;
    if (j < 2000 && kg < KKTOT) {
        int jy = j % 40, jx = j / 40;
        float why = ((float)jy * (200.0f/39.0f) - 100.0f) * 1e-3f;   // wh2[jy]
        float whx = ((float)jx * (200.0f/49.0f) - 100.0f) * 1e-3f;   // wh1[jx]
        float4 a0 = *(const float4*)(ay + kg);
        float4 a1 = *(const float4*)(ay + kg + 4);
        float4 b0 = *(const float4*)(ax + kg);
        float4 b1 = *(const float4*)(ax + kg + 4);
        float ayv[8] = {a0.x,a0.y,a0.z,a0.w,a1.x,a1.y,a1.z,a1.w};
        float axv[8] = {b0.x,b0.y,b0.z,b0.w,b1.x,b1.y,b1.z,b1.w};
        #pragma unroll
        for (int e = 0; e < 8; ++e) {
            float fr = phase_frac(ayv[e]-why, axv[e]-whx);
            cv[e] = (_Float16)__builtin_amdgcn_cosf(fr);
            sv[e] = (_Float16)__builtin_amdgcn_sinf(fr);
        }
    } else {
        #pragma unroll
        for (int e = 0; e < 8; ++e) { cv[e] = (_Float16)0.f; sv[e] = (_Float16)0.f; }
    }
    *(f16x8*)(C + o) = cv;
    *(f16x8*)(S + o) = sv;
}

// ---------------- UPPER-TRIANGLE fused Gram GEMM (compact grid, z=8, atomic epilogue) ----------------
// tile (mi<=ni):  R  += CtC + StS ;  Pm += CtS - StC   (accumulated via atomicAdd)
__global__ __launch_bounds__(256) void gemm_ut(const _Float16* __restrict__ C, const _Float16* __restrict__ S,
                                               float* __restrict__ R, float* __restrict__ Pm,
                                               int kiters, int kstride) {
    // compact triangle: blockIdx.x in [0,136) -> (mi, ni), mi<=ni
    int rem = blockIdx.x;
    int mi = 0;
    #pragma unroll
    for (int r = 0; r < 16; ++r) {
        int cnt = 16 - r;
        if (rem < cnt) { mi = r; break; }
        rem -= cnt;
    }
    const int ni = mi + rem;
    const int z = blockIdx.y;

    __shared__ _Float16 ldsCa[8192];  // [128 j][64 k] swizzled, 16KB each
    __shared__ _Float16 ldsSa[8192];
    __shared__ _Float16 ldsCb[8192];
    __shared__ _Float16 ldsSb[8192];
    const int t = threadIdx.x;
    const int w = t >> 6;
    const int lane = t & 63;

    f32x4 accR[4][4], accP[4][4];
    #pragma unroll
    for (int a = 0; a < 4; ++a)
        #pragma unroll
        for (int b = 0; b < 4; ++b) { accR[a][b] = (f32x4){0.f,0.f,0.f,0.f}; accP[a][b] = (f32x4){0.f,0.f,0.f,0.f}; }

    size_t aoff[4], boff[4];
    #pragma unroll
    for (int r = 0; r < 4; ++r) {
        int c = r * 256 + t;
        int jl = c >> 3;
        int ks = (c & 7) ^ (jl & 7);
        aoff[r] = (size_t)(mi*128 + jl) * kstride + ks*8;
        boff[r] = (size_t)(ni*128 + jl) * kstride + ks*8;
    }
    const int wm = w & 1, wn = w >> 1;
    const int q = lane >> 4, lm = lane & 15;
    const int ajl = wm*64 + lm;
    const int aoffl = (ajl*8 + (q ^ (ajl & 7))) * 16;
    const int bjl = wn*64 + lm;
    const int boffl = (bjl*8 + (q ^ (bjl & 7))) * 16;

    const int kq = kiters >> 3;                 // kiters divisible by 8 (Kc mult of 2048)
    for (int kt = z*kq; kt < (z+1)*kq; ++kt) {
        __syncthreads();
        const _Float16* gc = C + (size_t)kt * 64;
        const _Float16* gs = S + (size_t)kt * 64;
        #pragma unroll
        for (int r = 0; r < 4; ++r) {
            size_t dst = (size_t)(r*256 + w*64)*16;
            gload16(gc + aoff[r], (char*)ldsCa + dst);
            gload16(gs + aoff[r], (char*)ldsSa + dst);
            gload16(gc + boff[r], (char*)ldsCb + dst);
            gload16(gs + boff[r], (char*)ldsSb + dst);
        }
        __syncthreads();
        #pragma unroll
        for (int ks = 0; ks < 2; ++ks) {
            f16x8 bfC[4], bfS[4];
            #pragma unroll
            for (int nt = 0; nt < 4; ++nt) {
                bfC[nt] = *(const f16x8*)((const char*)ldsCb + ((boffl ^ (ks*64)) + nt*2048));
                bfS[nt] = *(const f16x8*)((const char*)ldsSb + ((boffl ^ (ks*64)) + nt*2048));
            }
            #pragma unroll
            for (int mt = 0; mt < 4; ++mt) {
                f16x8 afC = *(const f16x8*)((const char*)ldsCa + ((aoffl ^ (ks*64)) + mt*2048));
                f16x8 afS = *(const f16x8*)((const char*)ldsSa + ((aoffl ^ (ks*64)) + mt*2048));
                f16x8 nfS;
                #pragma unroll
                for (int e = 0; e < 8; ++e) nfS[e] = -afS[e];
                #pragma unroll
                for (int nt = 0; nt < 4; ++nt) {
                    accR[mt][nt] = __builtin_amdgcn_mfma_f32_16x16x32_f16(afC, bfC[nt], accR[mt][nt], 0, 0, 0);
                    accR[mt][nt] = __builtin_amdgcn_mfma_f32_16x16x32_f16(afS, bfS[nt], accR[mt][nt], 0, 0, 0);
                    accP[mt][nt] = __builtin_amdgcn_mfma_f32_16x16x32_f16(afC, bfS[nt], accP[mt][nt], 0, 0, 0);
                    accP[mt][nt] = __builtin_amdgcn_mfma_f32_16x16x32_f16(nfS, bfC[nt], accP[mt][nt], 0, 0, 0);
                }
            }
        }
    }
    #pragma unroll
    for (int mt = 0; mt < 4; ++mt) {
        #pragma unroll
        for (int nt = 0; nt < 4; ++nt) {
            int row0 = mi*128 + wm*64 + mt*16 + q*4;
            int col  = ni*128 + wn*64 + nt*16 + lm;
            float* rp = R  + (size_t)row0 * BAP + col;
            float* pp = Pm + (size_t)row0 * BAP + col;
            #pragma unroll
            for (int rr = 0; rr < 4; ++rr) {
                atomicAdd(rp + (size_t)rr * BAP, accR[mt][nt][rr]);
                atomicAdd(pp + (size_t)rr * BAP, accP[mt][nt][rr]);
            }
        }
    }
}

// ---------------- xd = DI * Hp^H rd ----------------
__global__ __launch_bounds__(256) void xd_init(const float* __restrict__ ay, const float* __restrict__ ax,
                                               const float* __restrict__ rd, float2* __restrict__ xd) {
    int j = blockIdx.x;
    int t = threadIdx.x;
    __shared__ float redr[256], redi[256];
    if (j >= 2000) { if (t == 0) xd[j] = make_float2(0.f, 0.f); return; }
    int jy = j % 40, jx = j / 40;
    float why = ((float)jy * (200.0f/39.0f) - 100.0f) * 1e-3f;
    float whx = ((float)jx * (200.0f/49.0f) - 100.0f) * 1e-3f;
    float sr = 0.f, si = 0.f;
    for (int i = t; i < KKTOT; i += 256) {
        float fr = phase_frac(ay[i]-why, ax[i]-whx);
        float r = rd[i];
        sr = fmaf(r, __builtin_amdgcn_cosf(fr), sr);
        si = fmaf(r, __builtin_amdgcn_sinf(fr), si);
    }
    redr[t] = sr; redi[t] = si;
    __syncthreads();
    for (int s2 = 128; s2 > 0; s2 >>= 1) {
        if (t < s2) { redr[t] += redr[t+s2]; redi[t] += redi[t+s2]; }
        __syncthreads();
    }
    if (t == 0) xd[j] = make_float2(0.01f * redr[0], -0.01f * redi[0]);
}

// ---------------- build G from upper-tri planes, Hermitian mirror (tiled, coalesced) ----------------
__global__ __launch_bounds__(256) void build_G_tile(const float* __restrict__ R, const float* __restrict__ Pm,
                                                    float2* __restrict__ G) {
    int ti = blockIdx.y, tj = blockIdx.x;
    if (tj < ti) return;
    __shared__ float2 tile[64][65];
    int t = threadIdx.x;
    #pragma unroll
    for (int r = 0; r < 16; ++r) {
        int e = t + 256*r;
        int lr = e >> 6, lc = e & 63;
        size_t mn = (size_t)(ti*64 + lr) * BAP + tj*64 + lc;
        float re = 0.01f * R[mn];
        float im = 0.01f * Pm[mn];
        G[mn] = make_float2(re, im);
        tile[lc][lr] = make_float2(re, -im);
    }
    if (tj == ti) return;
    __syncthreads();
    #pragma unroll
    for (int r = 0; r < 16; ++r) {
        int e = t + 256*r;
        int lr = e >> 6, lc = e & 63;
        G[(size_t)(tj*64 + lr) * BAP + ti*64 + lc] = tile[lr][lc];
    }
}

// ---------------- panel factorization (64x64 sequential core) — validated vs brute force ----------------
__global__ __launch_bounds__(256) void panel_factor(const float2* __restrict__ G, const float2* __restrict__ xd,
                                                    float2* __restrict__ Tp, float2* __restrict__ Wp,
                                                    float2* __restrict__ dinv, float2* __restrict__ v,
                                                    float* __restrict__ sarr, int p0) {
    __shared__ float2 Rcm[64*65];   // Rcm[c*65+i] = R[i][c]
    __shared__ float2 rowj[64];
    __shared__ float2 xdp[64];
    int t = threadIdx.x;
    int i = t & 63, cg = t >> 6;
    int cbase = cg * 16;
    #pragma unroll
    for (int r = 0; r < 16; ++r) {
        int e = t + 256*r;
        int ci = e & 63, ri = e >> 6;
        Rcm[ci*65 + ri] = G[(size_t)(p0+ri)*BAP + p0 + ci];
    }
    if (cg == 0) xdp[i] = xd[p0 + i];
    __syncthreads();
    for (int j = 0; j < 64; ++j) {
        float2 pr = Rcm[j*65 + j];
        float dr = 1.0f + pr.x, dii = pr.y;
        float idn = 1.0f / (dr*dr + dii*dii);
        float2 dv = make_float2(dr*idn, -dii*idn);
        float2 col = Rcm[j*65 + i];
        float2 tp = cmulf(col, dv);
        float2 vj = xdp[j];
        if (i == j) {
            for (int c = cbase; c < cbase+16; ++c) {
                float2 rv = Rcm[c*65 + j];
                rowj[c] = rv;
                Wp[j*64 + c] = rv;
            }
            if (cg == 0) { dinv[j] = dv; v[j] = vj; sarr[j] = dr; }
        }
        __syncthreads();
        for (int c = cbase; c < cbase+16; ++c) {
            float2 rj = rowj[c];
            float2 cur = Rcm[c*65 + i];
            cur.x -= tp.x*rj.x - tp.y*rj.y;
            cur.y -= tp.x*rj.y + tp.y*rj.x;
            Rcm[c*65 + i] = cur;
        }
        if (cg == 0) {
            Tp[i*64 + j] = tp;
            float2 xi = xdp[i];
            xi.x -= tp.x*vj.x - tp.y*vj.y;
            xi.y -= tp.x*vj.y + tp.y*vj.x;
            xdp[i] = xi;
        }
        __syncthreads();
    }
}

// ---------------- T (2048x64) recurrence + xd update (W derived from T elsewhere) ----------------
__global__ __launch_bounds__(64) void panel_T(const float2* __restrict__ G, float2* __restrict__ xd,
                                              float2* __restrict__ T,
                                              const float2* __restrict__ Wp,
                                              const float2* __restrict__ dinv, const float2* __restrict__ v, int p0) {
    __shared__ float2 src[64][64];
    __shared__ float2 loc[64][64];
    __shared__ float2 pan[64*64];    // Wp
    __shared__ float2 vloc[64], dloc[64];
    int t = threadIdx.x;
    for (int r = 0; r < 64; ++r) pan[r*64 + t] = Wp[r*64 + t];
    vloc[t] = v[t]; dloc[t] = dinv[t];
    int r = blockIdx.x * 64 + t;
    const float4* gp = (const float4*)(G + (size_t)r * BAP + p0);
    #pragma unroll
    for (int jj = 0; jj < 32; ++jj) {
        float4 qd = gp[jj];
        src[2*jj][t]   = make_float2(qd.x, qd.y);
        src[2*jj+1][t] = make_float2(qd.z, qd.w);
    }
    __syncthreads();
    float2 xacc = xd[r];
    for (int j = 0; j < 64; ++j) {
        float2 a = src[j][t];
        for (int k = 0; k < j; ++k) {
            float2 wkj = pan[k*64 + j];
            float2 lk = loc[k][t];
            a.x -= lk.x*wkj.x - lk.y*wkj.y;
            a.y -= lk.x*wkj.y + lk.y*wkj.x;
        }
        float2 tj = cmulf(a, dloc[j]);
        loc[j][t] = tj;
        T[(size_t)j * BAP + r] = tj;
        float2 vj = vloc[j];
        xacc.x -= tj.x*vj.x - tj.y*vj.y;
        xacc.y -= tj.x*vj.y + tj.y*vj.x;
    }
    xd[r] = xacc;
}

// ---------------- trailing update: G -= T*W, W[k][c] = s[k]*conj(T[k][c]) ----------------
__global__ __launch_bounds__(256) void trailing_update(float2* __restrict__ G,
                                                       const float2* __restrict__ T, const float* __restrict__ s) {
    __shared__ float2 Tb[16][128];   // [k][row] 16 KB
    __shared__ float2 Wb[16][64];    // [k][col] 8 KB
    int t = threadIdx.x;
    int cx = blockIdx.x * 64, ry = blockIdx.y * 128;
    int rq = t >> 4, cq = t & 15;
    float2 acc[8][4];
    #pragma unroll
    for (int si = 0; si < 8; ++si)
        #pragma unroll
        for (int u = 0; u < 4; ++u) acc[si][u] = make_float2(0.f, 0.f);

    for (int k0 = 0; k0 < 64; k0 += 16) {
        __syncthreads();
        #pragma unroll
        for (int r = 0; r < 4; ++r) {
            int e = t + 256*r;
            int k = e >> 6, x4 = e & 63;
            *(float4*)&Tb[k][x4*2] = *(const float4*)(T + (size_t)(k0+k) * BAP + ry + x4*2);
        }
        #pragma unroll
        for (int r = 0; r < 2; ++r) {
            int e = t + 256*r;
            int k = e >> 5, x4 = e & 31;
            float sk = s[k0+k];
            float4 tv = *(const float4*)(T + (size_t)(k0+k) * BAP + cx + x4*2);
            Wb[k][x4*2]   = make_float2(tv.x*sk, -tv.y*sk);
            Wb[k][x4*2+1] = make_float2(tv.z*sk, -tv.w*sk);
        }
        __syncthreads();
        #pragma unroll
        for (int k = 0; k < 16; ++k) {
            float2 av[8], bv[4];
            #pragma unroll
            for (int si = 0; si < 8; ++si) av[si] = Tb[k][rq + 16*si];
            #pragma unroll
            for (int u = 0; u < 4; ++u) bv[u] = Wb[k][cq + 16*u];
            #pragma unroll
            for (int si = 0; si < 8; ++si)
                #pragma unroll
                for (int u = 0; u < 4; ++u) {
                    acc[si][u].x = fmaf(av[si].x, bv[u].x, fmaf(-av[si].y, bv[u].y, acc[si][u].x));
                    acc[si][u].y = fmaf(av[si].x, bv[u].y, fmaf( av[si].y, bv[u].x, acc[si][u].y));
                }
        }
    }
    #pragma unroll
    for (int si = 0; si < 8; ++si) {
        float2* gp = G + (size_t)(ry + rq + 16*si) * BAP + cx + cq;
        #pragma unroll
        for (int u = 0; u < 4; ++u) {
            float2 gg = gp[16*u];
            gg.x -= acc[si][u].x;
            gg.y -= acc[si][u].y;
            gp[16*u] = gg;
        }
    }
}

// ---------------- finalize: out[b][a] = Re(xd[j]/G[j][j]), j = b*50+(49-a); f32 real plane ----------------
__global__ __launch_bounds__(256) void finalize_k(const float2* __restrict__ G, const float2* __restrict__ xd,
                                                  float* __restrict__ out, int out_size) {
    int o = blockIdx.x * 256 + threadIdx.x;
    if (o >= 2000) return;
    int b = o / 50, a = o % 50;
    int j = b * 50 + (49 - a);
    float2 x = xd[j];
    float2 g = G[(size_t)j * BAP + j];
    float den = 1.0f / (g.x*g.x + g.y*g.y);
    float re = (x.x*g.x + x.y*g.y) * den;
    float im = (x.y*g.x - x.x*g.y) * den;
    out[o] = re;
    if (out_size >= 4000) out[2000 + o] = im;
}

extern "C" void kernel_launch(void* const* d_in, const int* in_sizes, int n_in,
                              void* d_out, int out_size, void* d_ws, size_t ws_size,
                              hipStream_t stream) {
    const float* sar = (const float*)d_in[0];
    const int*   py  = (const int*)d_in[1];
    float* out = (float*)d_out;
    char* w = (char*)d_ws;
    size_t off = 0;
    auto take = [&](size_t sz) -> char* { char* p = w + off; off += (sz + 255) & ~(size_t)255; return p; };

    float*  R   = (float*)take((size_t)BAP*BAP*4);
    float*  Pm  = (float*)take((size_t)BAP*BAP*4);
    float2* G  = (float2*)take((size_t)BAP*BAP*8);
    float2* T  = (float2*)take((size_t)64*BAP*8);
    float2* xd = (float2*)take((size_t)BAP*8);
    float*  ay = (float*)take((size_t)KPADMAX*4);
    float*  ax = (float*)take((size_t)KPADMAX*4);
    float*  rd = (float*)take((size_t)KPADMAX*4);
    float2* Tp = (float2*)take(64*64*8);
    float2* Wp = (float2*)take(64*64*8);
    float2* dinv = (float2*)take(64*8);
    float2* vv   = (float2*)take(64*8);
    float*  sarr = (float*)take(64*4);

    size_t avail = (ws_size > off + 4096) ? (ws_size - off - 4096) : 0;
    long long Kc = (long long)(avail / 8192) & ~2047LL;   // 8192 B per k (2 f16 matrices x 2048 rows)
    if (Kc > KPADMAX) Kc = KPADMAX;
    if (Kc < 2048) Kc = 2048;
    int nch = (int)((KKTOT + Kc - 1) / Kc);
    // right-size Kc: smallest multiple of 2048 with nch*Kc >= KKTOT (minimize zero-padding)
    long long Kc2 = 2048LL * ((KKTOT + (long long)nch*2048 - 1) / ((long long)nch*2048));
    if (Kc2 >= 2048 && Kc2 <= Kc) Kc = Kc2;
    _Float16* C = (_Float16*)take((size_t)BAP * Kc * 2);
    _Float16* S = (_Float16*)take((size_t)BAP * Kc * 2);
    int kiters = (int)(Kc / 64);

    hipMemsetAsync(R, 0, (size_t)BAP*BAP*4*2, stream);  // R, Pm contiguous

    decode_k<<<dim3(391), dim3(256), 0, stream>>>(sar, py, ay, ax, rd);
    xd_init<<<dim3(BAP), dim3(256), 0, stream>>>(ay, ax, rd, xd);

    for (int c0 = 0; c0 < nch; ++c0) {
        gen_cs<<<dim3((unsigned)(Kc/2048), BAP), dim3(256), 0, stream>>>(C, S, ay, ax, (int)(c0*Kc), (int)Kc);
        gemm_ut<<<dim3(136, 8), dim3(256), 0, stream>>>(C, S, R, Pm, kiters, (int)Kc);
    }
    build_G_tile<<<dim3(32, 32), dim3(256), 0, stream>>>(R, Pm, G);

    for (int p = 0; p < 32; ++p) {
        int p0 = p * 64;
        panel_factor<<<dim3(1), dim3(256), 0, stream>>>(G, xd, Tp, Wp, dinv, vv, sarr, p0);
        panel_T<<<dim3(32), dim3(64), 0, stream>>>(G, xd, T, Wp, dinv, vv, p0);
        trailing_update<<<dim3(32, 16), dim3(256), 0, stream>>>(G, T, sarr);
    }
    finalize_k<<<dim3(8), dim3(256), 0, stream>>>(G, xd, out, out_size);
}